// Round 5
// baseline (568.183 us; speedup 1.0000x reference)
//
#include <hip/hip_runtime.h>
#include <hip/hip_bf16.h>
#include <stdint.h>

#define D 256
#define NBUCK 391            // ceil(100000 / 256) buckets of 256 nodes
#define BSHIFT 8
#define TILE 4096            // edges per block in binning pass

typedef short short8 __attribute__((ext_vector_type(8)));
typedef float f32x4 __attribute__((ext_vector_type(4)));
typedef unsigned int u32x2 __attribute__((ext_vector_type(2)));

__device__ __forceinline__ float bf2f(unsigned short u) {
  return __uint_as_float(((unsigned)u) << 16);
}
__device__ __forceinline__ unsigned short f2bf(float f) {
  unsigned u = __float_as_uint(f);
  unsigned r = u + 0x7FFFu + ((u >> 16) & 1u);
  return (unsigned short)(r >> 16);
}

// ---------------- K1: coarse bucket histogram (LDS-binned) ----------------
__global__ void bucket_hist_kernel(const int* __restrict__ src, int* __restrict__ bcount, int E) {
  __shared__ int h[NBUCK];
  for (int i = threadIdx.x; i < NBUCK; i += 256) h[i] = 0;
  __syncthreads();
  int gid = blockIdx.x * 256 + threadIdx.x;
  for (int e = gid; e < E; e += 256 * 256) atomicAdd(&h[src[e] >> BSHIFT], 1);
  __syncthreads();
  for (int i = threadIdx.x; i < NBUCK; i += 256) {
    int c = h[i];
    if (c) atomicAdd(&bcount[i], c);
  }
}

// ---------------- K2: exclusive scan of bucket counts ----------------
__global__ void bucket_scan_kernel(const int* __restrict__ bcount, int* __restrict__ bbase,
                                   int* __restrict__ gcursor) {
  __shared__ int sc[2][512];
  int tid = threadIdx.x;
  sc[0][tid] = (tid < NBUCK) ? bcount[tid] : 0;
  __syncthreads();
  int d = 0;
  for (int off = 1; off < 512; off <<= 1) {
    int v = sc[d][tid];
    if (tid >= off) v += sc[d][tid - off];
    sc[d ^ 1][tid] = v;
    __syncthreads();
    d ^= 1;
  }
  if (tid < NBUCK) {
    int excl = (tid == 0) ? 0 : sc[d][tid - 1];
    bbase[tid] = excl;
    gcursor[tid] = excl;
  }
}

// ---------------- K3: binning scatter ----------------
__launch_bounds__(256)
__global__ void binscatter_kernel(const int* __restrict__ src, const int* __restrict__ dst,
                                  int* __restrict__ gcursor, int* __restrict__ ebuf, int E) {
  __shared__ int hist[NBUCK];
  __shared__ int lstart[512];
  __shared__ int gbase[NBUCK];
  __shared__ int sc[2][512];
  __shared__ int stag[TILE];
  __shared__ unsigned short sbuck[TILE];

  int tid = threadIdx.x;
  int base = blockIdx.x * TILE;
  int tilecount = E - base;
  if (tilecount > TILE) tilecount = TILE;

  for (int i = tid; i < NBUCK; i += 256) hist[i] = 0;
  __syncthreads();

  int esrc[16], edst[16];
#pragma unroll
  for (int k = 0; k < 16; k++) {
    int e = base + k * 256 + tid;
    if (e < E) {
      esrc[k] = src[e];
      edst[k] = dst[e];
      atomicAdd(&hist[esrc[k] >> BSHIFT], 1);
    } else {
      esrc[k] = -1;
      edst[k] = 0;
    }
  }
  __syncthreads();

  for (int i = tid; i < 512; i += 256) sc[0][i] = (i < NBUCK) ? hist[i] : 0;
  __syncthreads();
  int d = 0;
  for (int off = 1; off < 512; off <<= 1) {
    for (int i = tid; i < 512; i += 256) {
      int v = sc[d][i];
      if (i >= off) v += sc[d][i - off];
      sc[d ^ 1][i] = v;
    }
    __syncthreads();
    d ^= 1;
  }
  for (int i = tid; i < 512; i += 256) lstart[i] = (i == 0) ? 0 : sc[d][i - 1];
  __syncthreads();

  for (int b = tid; b < NBUCK; b += 256) {
    int c = hist[b];
    if (c) gbase[b] = atomicAdd(&gcursor[b], c);
  }
  __syncthreads();

  for (int i = tid; i < NBUCK; i += 256) hist[i] = 0;
  __syncthreads();

#pragma unroll
  for (int k = 0; k < 16; k++) {
    if (esrc[k] >= 0) {
      int b = esrc[k] >> BSHIFT;
      int r = atomicAdd(&hist[b], 1);
      int pos = lstart[b] + r;
      stag[pos] = edst[k] | ((esrc[k] & 255) << 20);
      sbuck[pos] = (unsigned short)b;
    }
  }
  __syncthreads();

  for (int s = tid; s < tilecount; s += 256) {
    int b = sbuck[s];
    ebuf[gbase[b] + (s - lstart[b])] = stag[s];
  }
}

// ---------------- K4: per-bucket counting sort ----------------
__launch_bounds__(256)
__global__ void bucketsort_kernel(const int* __restrict__ ebuf, const int* __restrict__ bbase,
                                  const int* __restrict__ bcount, int* __restrict__ csr,
                                  int2* __restrict__ meta, float* __restrict__ rnorm, int N) {
  __shared__ int ncnt[256];
  __shared__ int nstart[256];
  __shared__ int sc[2][256];
  int tid = threadIdx.x;
  int b = blockIdx.x;
  int base = bbase[b];
  int cnt = bcount[b];
  int node0 = b << BSHIFT;

  ncnt[tid] = 0;
  __syncthreads();
  for (int s = tid; s < cnt; s += 256) {
    int v = ebuf[base + s];
    atomicAdd(&ncnt[v >> 20], 1);
  }
  __syncthreads();

  int mycnt = ncnt[tid];
  sc[0][tid] = mycnt;
  __syncthreads();
  int d = 0;
  for (int off = 1; off < 256; off <<= 1) {
    int v = sc[d][tid];
    if (tid >= off) v += sc[d][tid - off];
    sc[d ^ 1][tid] = v;
    __syncthreads();
    d ^= 1;
  }
  nstart[tid] = (tid == 0) ? 0 : sc[d][tid - 1];
  __syncthreads();

  int node = node0 + tid;
  if (node < N) {
    meta[node] = make_int2(base + nstart[tid], mycnt);
    rnorm[node] = rsqrtf((float)(mycnt + 1));
  }

  ncnt[tid] = 0;
  __syncthreads();
  for (int s = tid; s < cnt; s += 256) {
    int v = ebuf[base + s];
    int nl = v >> 20;
    int r = atomicAdd(&ncnt[nl], 1);
    csr[base + nstart[nl] + r] = v & 0xFFFFF;
  }
}

// ---------------- fp32 -> bf16 conversion for W only ----------------
__global__ void convw_kernel(const float* __restrict__ w, unsigned short* __restrict__ wb) {
  int i4 = blockIdx.x * 256 + threadIdx.x;
  int elem = i4 * 4;
  const float4 v = *(const float4*)&w[elem];
  ushort4 o;
  o.x = f2bf(v.x); o.y = f2bf(v.y); o.z = f2bf(v.z); o.w = f2bf(v.w);
  *(ushort4*)&wb[elem] = o;
}

// ---------------- fused bf16 MFMA GEMM: hs = rsqrt(deg) * (x @ W^T) ----------
// BN = 256: one block computes 128 rows x all 256 cols, so the f32 A-panel is
// read exactly once (fuses the old convx kernel; x converted in-register).
// Row-major output [npad][256]; pad rows (gr >= n): staged as zeros AND
// scaled by rn = 0 -> hb pad rows are zeros (gather's row-n sentinel).
__launch_bounds__(256)
__global__ void gemm_kernel(const float* __restrict__ X,
                            const unsigned short* __restrict__ B,
                            unsigned short* __restrict__ Hout,
                            const float* __restrict__ rnorm, int n) {
  __shared__ unsigned short sA[128 * 32];
  __shared__ unsigned short sB[256 * 32];
  int tid = threadIdx.x;
  int wave = tid >> 6, lane = tid & 63;
  int wm = wave >> 1, wn = wave & 1;      // 2x2 wave grid: 64 rows x 128 cols each
  int l16 = lane & 15, quad = lane >> 4;
  int arow0 = blockIdx.x * 128;

  f32x4 acc[4][8];
  const f32x4 zero = {0.f, 0.f, 0.f, 0.f};
#pragma unroll
  for (int i = 0; i < 4; i++)
#pragma unroll
    for (int j = 0; j < 8; j++) acc[i][j] = zero;

  for (int k0 = 0; k0 < 256; k0 += 32) {
    // A: 128x32 staged from f32 x with in-register bf16 convert
#pragma unroll
    for (int it = 0; it < 2; ++it) {
      int c = it * 256 + tid;
      int row = c >> 2, cc = (c & 3) * 8;
      int grow = arow0 + row;
      ushort4 lo = make_ushort4(0, 0, 0, 0), hi = make_ushort4(0, 0, 0, 0);
      if (grow < n) {
        const float4 v0 = *(const float4*)&X[(size_t)grow * 256 + k0 + cc];
        const float4 v1 = *(const float4*)&X[(size_t)grow * 256 + k0 + cc + 4];
        lo.x = f2bf(v0.x); lo.y = f2bf(v0.y); lo.z = f2bf(v0.z); lo.w = f2bf(v0.w);
        hi.x = f2bf(v1.x); hi.y = f2bf(v1.y); hi.z = f2bf(v1.z); hi.w = f2bf(v1.w);
      }
      *(ushort4*)&sA[c * 8] = lo;
      *(ushort4*)&sA[c * 8 + 4] = hi;
    }
    // B: 256x32 from bf16 wb (L2-resident, converted once by convw)
#pragma unroll
    for (int it = 0; it < 4; ++it) {
      int c = it * 256 + tid;
      int row = c >> 2, cc = (c & 3) * 8;
      *(int4*)&sB[c * 8] = *(const int4*)&B[row * 256 + k0 + cc];
    }
    __syncthreads();
    short8 af[4], bfr[8];
#pragma unroll
    for (int i = 0; i < 4; i++)
      af[i] = *(const short8*)&sA[(wm * 64 + i * 16 + l16) * 32 + quad * 8];
#pragma unroll
    for (int j = 0; j < 8; j++)
      bfr[j] = *(const short8*)&sB[(wn * 128 + j * 16 + l16) * 32 + quad * 8];
#pragma unroll
    for (int i = 0; i < 4; i++)
#pragma unroll
      for (int j = 0; j < 8; j++)
        acc[i][j] = __builtin_amdgcn_mfma_f32_16x16x32_bf16(af[i], bfr[j], acc[i][j], 0, 0, 0);
    __syncthreads();
  }

#pragma unroll
  for (int i = 0; i < 4; i++) {
    int rowb = arow0 + wm * 64 + i * 16 + quad * 4;
#pragma unroll
    for (int r = 0; r < 4; r++) {
      int gr = rowb + r;
      float rn = (gr < n) ? rnorm[gr] : 0.f;
#pragma unroll
      for (int j = 0; j < 8; j++) {
        int col = wn * 128 + j * 16 + l16;
        Hout[(size_t)gr * 256 + col] = f2bf(acc[i][j][r] * rn);
      }
    }
  }
}

// ---------------- full-row CSR gather: 1 wave-load = 1 edge = 512 B ----------
// At the measured per-CU line-issue floor (~6 cyc / 64 B line beyond L1):
// E x 8 lines = 25.6 M lines -> ~250 us predicted, 242 us measured. Do not
// touch: residency (r3) and load-width (r0 vs r4) both proven non-levers.
__launch_bounds__(256)
__global__ void gather_kernel(const unsigned short* __restrict__ hs,
                              const int2* __restrict__ meta,
                              const float* __restrict__ rnorm,
                              const int* __restrict__ csr,
                              float* __restrict__ out, int n) {
  const int wave = threadIdx.x >> 6;
  const int lane = threadIdx.x & 63;
  const int node = blockIdx.x * 4 + wave;
  if (node >= n) return;
  long long mm = __builtin_nontemporal_load((const long long*)&meta[node]);
  const int start = (int)mm;
  const int cnt = (int)(mm >> 32);
  const int loff = lane << 2;   // ushort offset within row: lane*4 cols = 8 B

  float a0 = 0.f, a1 = 0.f, a2 = 0.f, a3 = 0.f;

#define GRP16(G)                                                          \
  {                                                                       \
    u32x2 v[16];                                                          \
    _Pragma("unroll")                                                     \
    for (int u = 0; u < 16; ++u) {                                        \
      int r = __builtin_amdgcn_readlane(idxv, (G) + u);                   \
      v[u] = *(const u32x2*)&hs[((size_t)r << 8) + loff];                 \
    }                                                                     \
    _Pragma("unroll")                                                     \
    for (int u = 0; u < 16; ++u) {                                        \
      a0 += bf2f((unsigned short)v[u][0]);                                \
      a1 += bf2f((unsigned short)(v[u][0] >> 16));                        \
      a2 += bf2f((unsigned short)v[u][1]);                                \
      a3 += bf2f((unsigned short)(v[u][1] >> 16));                        \
    }                                                                     \
  }

  // csr is padded by 64 entries, so the chunk loads below never fault.
  int idxv = __builtin_nontemporal_load(&csr[start + lane]);
  int base = 0;
  while (base + 64 <= cnt) {
    int idxn = __builtin_nontemporal_load(&csr[start + base + 64 + lane]);
    GRP16(0) GRP16(16) GRP16(32) GRP16(48)
    idxv = idxn;
    base += 64;
  }
  int m = cnt - base;           // 0..63 remaining, already staged in idxv
  int g = 0;
  for (; g + 16 <= m; g += 16) GRP16(g)
  for (; g < m; ++g) {
    int r = __builtin_amdgcn_readlane(idxv, g);
    u32x2 v = *(const u32x2*)&hs[((size_t)r << 8) + loff];
    a0 += bf2f((unsigned short)v[0]);
    a1 += bf2f((unsigned short)(v[0] >> 16));
    a2 += bf2f((unsigned short)v[1]);
    a3 += bf2f((unsigned short)(v[1] >> 16));
  }
#undef GRP16

  // self term + final scale
  u32x2 us = *(const u32x2*)&hs[((size_t)node << 8) + loff];
  float rn = __builtin_nontemporal_load(&rnorm[node]);
  f32x4 o;
  o[0] = rn * (a0 + bf2f((unsigned short)us[0]));
  o[1] = rn * (a1 + bf2f((unsigned short)(us[0] >> 16)));
  o[2] = rn * (a2 + bf2f((unsigned short)us[1]));
  o[3] = rn * (a3 + bf2f((unsigned short)(us[1] >> 16)));
  __builtin_nontemporal_store(o, (f32x4*)&out[(size_t)node * 256 + loff]);
}

extern "C" void kernel_launch(void* const* d_in, const int* in_sizes, int n_in,
                              void* d_out, int out_size, void* d_ws, size_t ws_size,
                              hipStream_t stream) {
  const float* x = (const float*)d_in[0];
  const float* W = (const float*)d_in[1];
  const int* ei = (const int*)d_in[2];
  float* out = (float*)d_out;

  int N = in_sizes[0] / D;        // 100000
  int E = in_sizes[2] / 2;        // 3200000
  int NPAD = (N + 127) & ~127;
  const int* src = ei;
  const int* dst = ei + E;

  char* p = (char*)d_ws;
  auto alloc = [&](size_t b) {
    char* r = p;
    p += (b + 255) & ~(size_t)255;
    return r;
  };
  unsigned short* wb = (unsigned short*)alloc((size_t)D * D * 2);
  unsigned short* hb = (unsigned short*)alloc((size_t)NPAD * D * 2);
  int* csr = (int*)alloc((size_t)(E + 64) * 4);   // +64 pad: chunk loads never fault
  int2* meta = (int2*)alloc((size_t)N * 8);
  float* rnorm = (float*)alloc((size_t)N * 4);
  int* bcount = (int*)alloc(NBUCK * 4);
  int* bbase = (int*)alloc(NBUCK * 4);
  int* gcursor = (int*)alloc(NBUCK * 4);
  // ebuf (E*4 = 12.8 MB) aliases hb (51 MB): dead before gemm writes hb
  int* ebuf = (int*)hb;

  hipMemsetAsync(bcount, 0, NBUCK * 4, stream);
  bucket_hist_kernel<<<256, 256, 0, stream>>>(src, bcount, E);
  bucket_scan_kernel<<<1, 512, 0, stream>>>(bcount, bbase, gcursor);
  binscatter_kernel<<<(E + TILE - 1) / TILE, 256, 0, stream>>>(src, dst, gcursor, ebuf, E);
  bucketsort_kernel<<<NBUCK, 256, 0, stream>>>(ebuf, bbase, bcount, csr, meta, rnorm, N);
  convw_kernel<<<(D * D / 4) / 256, 256, 0, stream>>>(W, wb);
  gemm_kernel<<<NPAD / 128, 256, 0, stream>>>(x, wb, hb, rnorm, N);
  gather_kernel<<<(N + 3) / 4, 256, 0, stream>>>(hb, meta, rnorm, csr, out, N);
}